// Round 8
// baseline (231.009 us; speedup 1.0000x reference)
//
#include <hip/hip_runtime.h>
#include <hip/hip_bf16.h>
#include <math.h>

#define BATCH 16
#define NPTS 10000
#define HID 128
#define NOUT 5
#define TM 64
#define TPB 256

typedef unsigned short ushort_t;
typedef __attribute__((ext_vector_type(8))) short short8;      // 8 bf16 = 4 VGPRs
typedef __attribute__((ext_vector_type(4))) float f32x4;       // MFMA C/D

__device__ __forceinline__ float fast_tanh(float x) {
    float e = __expf(2.0f * x);
    return 1.0f - 2.0f / (e + 1.0f);
}
__device__ __forceinline__ float rowdy_act(float x, float a, float w) {
    return fast_tanh(x) + a * __sinf(w * x);
}
__device__ __forceinline__ ushort_t f32_to_bf16_rn(float f) {
    unsigned u = __float_as_uint(f);
    unsigned r = (u + 0x7FFFu + ((u >> 16) & 1u)) >> 16;
    return (ushort_t)r;
}
__device__ __forceinline__ float bf16_to_f32(ushort_t u) {
    return __uint_as_float(((unsigned)u) << 16);
}

// ============ Fused prep (blocks 0-2) + branch (blocks 3-18, LDS-staged weights) ============
__global__ __launch_bounds__(256) void prep_branch_kernel(
    const float* __restrict__ Wt, ushort_t* __restrict__ whi, ushort_t* __restrict__ wlo,
    const float* __restrict__ params, const float* __restrict__ Wb0, const float* __restrict__ bb0,
    const float* __restrict__ Wb, const float* __restrict__ bb,
    const float* __restrict__ Wbf, const float* __restrict__ bbf,
    const float* __restrict__ ab, const float* __restrict__ wb,
    const float* __restrict__ Wtf, const float* __restrict__ btf,
    float* __restrict__ g_gates, float* __restrict__ g_wcomb, float* __restrict__ g_bcomb)
{
    __shared__ __align__(16) float wsh[HID * HID];   // 64 KB staging (prep AND branch)
    __shared__ float hbuf[HID];
    __shared__ float bcbuf[NOUT][HID];

    const int tid = threadIdx.x;

    if (blockIdx.x < 3) {
        // ---------------- prep: one block per trunk layer ----------------
        // swizzle into MFMA B-fragment order, bf16 hi (RN) + lo (RN of remainder)
        // frag flat idx = (((l*8 + t)*4 + s)*64 + lam)*8 + j
        // maps W[l][k = s*32 + (lam>>4)*8 + j][n = t*16 + (lam&15)]
        const int l = blockIdx.x;
        const float4* src = (const float4*)(Wt + l * HID * HID);
        #pragma unroll
        for (int i = 0; i < 16; i++)
            ((float4*)wsh)[i * 256 + tid] = src[i * 256 + tid];
        __syncthreads();
        for (int e = tid; e < 2048; e += 256) {
            int t = e >> 8, s = (e >> 6) & 3, lam = e & 63;
            int k0 = s * 32 + (lam >> 4) * 8;
            int n = t * 16 + (lam & 15);
            short8 h8, l8;
            #pragma unroll
            for (int j = 0; j < 8; j++) {
                float v = wsh[(k0 + j) * HID + n];
                ushort_t h = f32_to_bf16_rn(v);
                float rem = v - bf16_to_f32(h);
                h8[j] = (short)h;
                l8[j] = (short)f32_to_bf16_rn(rem);
            }
            ((short8*)whi)[l * 2048 + e] = h8;
            ((short8*)wlo)[l * 2048 + e] = l8;
        }
        return;
    }

    // ---------------- branch: one block per batch, LDS-staged weights ----------------
    const int b = blockIdx.x - 3;
    const int j = tid & 127;
    const bool act = (tid < 128);

    // L0 (K=6)
    float z = bb0[j];
    #pragma unroll
    for (int k = 0; k < 6; k++) z += params[b * 6 + k] * Wb0[k * HID + j];
    float h = rowdy_act(z, ab[j], wb[j]);
    float g = h;
    if (act) {
        g_gates[b * 4 * HID + j] = g;
        hbuf[j] = h;
    }
    __syncthreads();

    // 3 hidden layers: stage Wb[i] (64 KB) -> LDS, compute from LDS
    for (int i = 0; i < 3; i++) {
        const float4* src = (const float4*)(Wb + i * HID * HID);
        for (int t = tid; t < HID * HID / 4; t += 256)
            ((float4*)wsh)[t] = src[t];
        __syncthreads();
        float z0 = 0.f, z1 = 0.f, z2 = 0.f, z3 = 0.f;
        #pragma unroll 8
        for (int k = 0; k < HID; k += 4) {
            z0 += hbuf[k + 0] * wsh[(k + 0) * HID + j];
            z1 += hbuf[k + 1] * wsh[(k + 1) * HID + j];
            z2 += hbuf[k + 2] * wsh[(k + 2) * HID + j];
            z3 += hbuf[k + 3] * wsh[(k + 3) * HID + j];
        }
        float zz = bb[i * HID + j] + ((z0 + z1) + (z2 + z3));
        float hn = rowdy_act(zz, ab[(i + 1) * HID + j], wb[(i + 1) * HID + j]);
        g += hn;
        if (act) g_gates[b * 4 * HID + (i + 1) * HID + j] = g;
        __syncthreads();          // all reads of wsh & hbuf done
        if (act) hbuf[j] = hn;
        __syncthreads();
    }

    // branch_out: h3 @ Wbf (128x640) in five 64 KB column-chunks
    float bo[NOUT];
    #pragma unroll
    for (int o = 0; o < NOUT; o++) bo[o] = bbf[o * HID + j];
    for (int o = 0; o < NOUT; o++) {
        const float4* Wbf4 = (const float4*)Wbf;
        for (int t = tid; t < 4096; t += 256) {
            int k = t >> 5, c = t & 31;
            ((float4*)wsh)[t] = Wbf4[k * 160 + o * 32 + c];
        }
        __syncthreads();
        float s0 = 0.f, s1 = 0.f, s2 = 0.f, s3 = 0.f;
        #pragma unroll 8
        for (int k = 0; k < HID; k += 4) {
            s0 += hbuf[k + 0] * wsh[(k + 0) * HID + j];
            s1 += hbuf[k + 1] * wsh[(k + 1) * HID + j];
            s2 += hbuf[k + 2] * wsh[(k + 2) * HID + j];
            s3 += hbuf[k + 3] * wsh[(k + 3) * HID + j];
        }
        bo[o] += (s0 + s1) + (s2 + s3);
        __syncthreads();          // before restaging wsh
    }
    if (act) {
        #pragma unroll
        for (int o = 0; o < NOUT; o++) bcbuf[o][j] = bo[o];
    }
    __syncthreads();

    // Wcomb[b][j][o] = sum_h Wtf[j][h] * bc[o][h]  (row-major float4 reads of Wtf)
    float wc[NOUT] = {0.f, 0.f, 0.f, 0.f, 0.f};
    const float4* WtfR = (const float4*)(Wtf + j * HID);
    #pragma unroll 4
    for (int h4 = 0; h4 < 32; h4++) {
        float4 wv = WtfR[h4];
        int h2 = h4 * 4;
        #pragma unroll
        for (int o = 0; o < NOUT; o++) {
            wc[o] += wv.x * bcbuf[o][h2] + wv.y * bcbuf[o][h2 + 1]
                   + wv.z * bcbuf[o][h2 + 2] + wv.w * bcbuf[o][h2 + 3];
        }
    }
    if (act) {
        #pragma unroll
        for (int o = 0; o < NOUT; o++) g_wcomb[b * HID * NOUT + j * NOUT + o] = wc[o];
    }
    if (tid < NOUT) {
        float acc = 0.f;
        for (int h2 = 0; h2 < HID; h2++) acc += btf[h2] * bcbuf[tid][h2];
        g_bcomb[b * NOUT + tid] = acc;
    }
}

// ============ Trunk kernel: round-6 version VERBATIM (known-good) ============
__global__ __launch_bounds__(TPB, 3) void trunk_kernel(
    const float* __restrict__ coords, const float* __restrict__ sdf,
    const float* __restrict__ Wt0, const float* __restrict__ bt0,
    const float* __restrict__ bt, const float* __restrict__ at, const float* __restrict__ wt,
    const float* __restrict__ g_gates, const float* __restrict__ g_wcomb,
    const float* __restrict__ g_bcomb,
    const ushort_t* __restrict__ whi, const ushort_t* __restrict__ wlo,
    float* __restrict__ out)
{
    // activations in MFMA A-fragment order:
    //   idx = ((mt*4 + s)*64 + lam)*8 + j  <->  x[row = mt*16+(lam&15)][col = s*32+(lam>>4)*8+j]
    __shared__ __align__(16) ushort_t xfh[TM * HID];            // 16 KB bf16 hi (truncated)
    __shared__ __align__(16) ushort_t xfl[TM * HID];            // 16 KB bf16 lo (truncated remainder)
    __shared__ __align__(16) float sb_bias[4][HID];
    __shared__ __align__(16) float sb_a[4][HID];
    __shared__ __align__(16) float sb_w[4][HID];
    __shared__ __align__(16) float sb_g[4][HID];
    __shared__ __align__(16) float Wt0s[4][HID];
    __shared__ __align__(16) float Wc[NOUT][HID];
    __shared__ float bcs[NOUT];
    __shared__ __align__(16) float xin[TM][4];
    __shared__ float redbuf[4][TM][NOUT];

    const int b = blockIdx.y;
    const int p0 = blockIdx.x * TM;
    const int tid = threadIdx.x;
    const int w = tid >> 6;              // wave id = s-group (layer0) / n-group (layers 1-3)
    const int lam = tid & 63;
    const int quad = lam >> 4, lq = lam & 15;

    // ---- stage tables ----
    for (int idx = tid; idx < 4 * HID; idx += TPB) {
        int l = idx >> 7, jj = idx & (HID - 1);
        sb_bias[l][jj] = (l == 0) ? bt0[jj] : bt[(l - 1) * HID + jj];
        sb_a[l][jj] = at[idx];
        sb_w[l][jj] = wt[idx];
        sb_g[l][jj] = g_gates[b * 4 * HID + idx];
        Wt0s[l][jj] = Wt0[idx];
    }
    for (int idx = tid; idx < HID * NOUT; idx += TPB) {
        int k = idx / NOUT, o = idx - k * NOUT;
        Wc[o][k] = g_wcomb[b * HID * NOUT + idx];
    }
    if (tid < NOUT) bcs[tid] = g_bcomb[b * NOUT + tid];

    if (tid < 192) {
        int p = tid / 3, c = tid - p * 3;
        int gp = p0 + p;
        xin[p][c] = (gp < NPTS) ? coords[(size_t)(b * NPTS + gp) * 3 + c] : 0.0f;
    } else {
        int p = tid - 192;
        int gp = p0 + p;
        xin[p][3] = (gp < NPTS) ? sdf[b * NPTS + gp] : 0.0f;
    }
    __syncthreads();

    // ---- layer 0 (K=4) on VALU, write bf16 hi/lo fragments (linear b128 stores) ----
    {
        const int s = w;
        float w0c[8], w1c[8], w2c[8], w3c[8], bc8[8], ac[8], wc8[8], gc[8];
        #pragma unroll
        for (int jj = 0; jj < 8; jj++) {
            int col = s * 32 + quad * 8 + jj;
            w0c[jj] = Wt0s[0][col];
            w1c[jj] = Wt0s[1][col];
            w2c[jj] = Wt0s[2][col];
            w3c[jj] = Wt0s[3][col];
            bc8[jj] = sb_bias[0][col];
            ac[jj] = sb_a[0][col];
            wc8[jj] = sb_w[0][col];
            gc[jj] = sb_g[0][col];
        }
        #pragma unroll
        for (int mt = 0; mt < 4; mt++) {
            int row = mt * 16 + lq;
            float4 xi = *(const float4*)&xin[row][0];
            float y[8];
            #pragma unroll
            for (int jj = 0; jj < 8; jj++) {
                float zv = xi.x * w0c[jj] + xi.y * w1c[jj] + xi.z * w2c[jj] + xi.w * w3c[jj] + bc8[jj];
                y[jj] = rowdy_act(zv, ac[jj], wc8[jj]) * gc[jj];
            }
            uint4 hp, lp;
            unsigned* hpp = (unsigned*)&hp;
            unsigned* lpp = (unsigned*)&lp;
            #pragma unroll
            for (int pr = 0; pr < 4; pr++) {
                unsigned ue = __float_as_uint(y[2 * pr]);
                unsigned uo = __float_as_uint(y[2 * pr + 1]);
                hpp[pr] = (ue >> 16) | (uo & 0xFFFF0000u);
                float le = y[2 * pr] - __uint_as_float(ue & 0xFFFF0000u);
                float lo_ = y[2 * pr + 1] - __uint_as_float(uo & 0xFFFF0000u);
                lpp[pr] = (__float_as_uint(le) >> 16) | (__float_as_uint(lo_) & 0xFFFF0000u);
            }
            *(uint4*)&xfh[((mt * 4 + s) * 64 + lam) * 8] = hp;
            *(uint4*)&xfl[((mt * 4 + s) * 64 + lam) * 8] = lp;
        }
    }
    __syncthreads();

    // ---- layers 1..3 on MFMA 16x16x32 bf16, single accumulator, 3 terms:
    //      acc = xh*Wh + xl*Wh + xh*Wl  (bias in C-init; dropped xl*Wl ~ 2^-15 rel)
    const short8* Wh8 = (const short8*)whi;
    const short8* Wl8 = (const short8*)wlo;
    // epilogue scatter constants
    const int lq3 = lq >> 3;
    const int jlow = lq & 7;
    const int ebase0 = w * 512 + (lq3 * 16 + quad * 4) * 8 + jlow;          // nt = 2w
    const int ebase1 = w * 512 + ((2 + lq3) * 16 + quad * 4) * 8 + jlow;    // nt = 2w+1
    const int n0 = 32 * w + lq, n1 = 32 * w + 16 + lq;

    for (int l = 1; l <= 3; l++) {
        const int fb = (l - 1) * 32;
        float b0 = sb_bias[l][n0], b1 = sb_bias[l][n1];
        f32x4 acc[4][2];
        #pragma unroll
        for (int mt = 0; mt < 4; mt++) {
            acc[mt][0] = (f32x4){b0, b0, b0, b0};
            acc[mt][1] = (f32x4){b1, b1, b1, b1};
        }
        for (int s = 0; s < 4; s++) {
            short8 bh0 = Wh8[(size_t)(fb + (2 * w) * 4 + s) * 64 + lam];
            short8 bl0 = Wl8[(size_t)(fb + (2 * w) * 4 + s) * 64 + lam];
            short8 bh1 = Wh8[(size_t)(fb + (2 * w + 1) * 4 + s) * 64 + lam];
            short8 bl1 = Wl8[(size_t)(fb + (2 * w + 1) * 4 + s) * 64 + lam];
            #pragma unroll
            for (int mt = 0; mt < 4; mt++) {
                short8 ah = *(const short8*)&xfh[((mt * 4 + s) * 64 + lam) * 8];
                short8 al = *(const short8*)&xfl[((mt * 4 + s) * 64 + lam) * 8];
                acc[mt][0] = __builtin_amdgcn_mfma_f32_16x16x32_bf16(ah, bh0, acc[mt][0], 0, 0, 0);
                acc[mt][0] = __builtin_amdgcn_mfma_f32_16x16x32_bf16(al, bh0, acc[mt][0], 0, 0, 0);
                acc[mt][0] = __builtin_amdgcn_mfma_f32_16x16x32_bf16(ah, bl0, acc[mt][0], 0, 0, 0);
                acc[mt][1] = __builtin_amdgcn_mfma_f32_16x16x32_bf16(ah, bh1, acc[mt][1], 0, 0, 0);
                acc[mt][1] = __builtin_amdgcn_mfma_f32_16x16x32_bf16(al, bh1, acc[mt][1], 0, 0, 0);
                acc[mt][1] = __builtin_amdgcn_mfma_f32_16x16x32_bf16(ah, bl1, acc[mt][1], 0, 0, 0);
            }
        }
        __syncthreads();   // all waves done reading xfh/xfl for this layer
        float a0 = sb_a[l][n0], ww0 = sb_w[l][n0], gg0 = sb_g[l][n0];
        float a1 = sb_a[l][n1], ww1 = sb_w[l][n1], gg1 = sb_g[l][n1];
        #pragma unroll
        for (int mt = 0; mt < 4; mt++) {
            #pragma unroll
            for (int r = 0; r < 4; r++) {
                float y0 = rowdy_act(acc[mt][0][r], a0, ww0) * gg0;
                float y1 = rowdy_act(acc[mt][1][r], a1, ww1) * gg1;
                unsigned u0 = __float_as_uint(y0);
                unsigned u1 = __float_as_uint(y1);
                float l0f = y0 - __uint_as_float(u0 & 0xFFFF0000u);
                float l1f = y1 - __uint_as_float(u1 & 0xFFFF0000u);
                xfh[mt * 2048 + ebase0 + r * 8] = (ushort_t)(u0 >> 16);
                xfl[mt * 2048 + ebase0 + r * 8] = (ushort_t)(__float_as_uint(l0f) >> 16);
                xfh[mt * 2048 + ebase1 + r * 8] = (ushort_t)(u1 >> 16);
                xfl[mt * 2048 + ebase1 + r * 8] = (ushort_t)(__float_as_uint(l1f) >> 16);
            }
        }
        __syncthreads();
    }

    // ---- final: out[p][o] = (hi+lo)(p,:) . Wc[o,:] + bcomb[o], k-split 4 ways ----
    {
        int q = tid & 3, p = tid >> 2;
        int mt = p >> 4, prow = p & 15;
        float part[NOUT] = {0.f, 0.f, 0.f, 0.f, 0.f};
        #pragma unroll
        for (int g8 = 0; g8 < 4; g8++) {
            int base = ((mt * 4 + q) * 64 + g8 * 16 + prow) * 8;
            uint4 h4 = *(const uint4*)&xfh[base];
            uint4 l4 = *(const uint4*)&xfl[base];
            const unsigned* hu = (const unsigned*)&h4;
            const unsigned* lu = (const unsigned*)&l4;
            int c0 = q * 32 + g8 * 8;
            float xv[8];
            #pragma unroll
            for (int pr = 0; pr < 4; pr++) {
                xv[2 * pr]     = __uint_as_float(hu[pr] << 16) + __uint_as_float(lu[pr] << 16);
                xv[2 * pr + 1] = __uint_as_float(hu[pr] & 0xFFFF0000u) + __uint_as_float(lu[pr] & 0xFFFF0000u);
            }
            #pragma unroll
            for (int o = 0; o < NOUT; o++) {
                float4 wa = *(const float4*)&Wc[o][c0];
                float4 wb4 = *(const float4*)&Wc[o][c0 + 4];
                part[o] += xv[0] * wa.x + xv[1] * wa.y + xv[2] * wa.z + xv[3] * wa.w
                         + xv[4] * wb4.x + xv[5] * wb4.y + xv[6] * wb4.z + xv[7] * wb4.w;
            }
        }
        #pragma unroll
        for (int o = 0; o < NOUT; o++) redbuf[q][p][o] = part[o];
    }
    __syncthreads();
    if (tid < TM) {
        int gp = p0 + tid;
        if (gp < NPTS) {
            #pragma unroll
            for (int o = 0; o < NOUT; o++) {
                float s = bcs[o] + redbuf[0][tid][o] + redbuf[1][tid][o]
                                 + redbuf[2][tid][o] + redbuf[3][tid][o];
                out[(size_t)(b * NPTS + gp) * NOUT + o] = s;
            }
        }
    }
}

extern "C" void kernel_launch(void* const* d_in, const int* in_sizes, int n_in,
                              void* d_out, int out_size, void* d_ws, size_t ws_size,
                              hipStream_t stream) {
    (void)in_sizes; (void)n_in; (void)out_size; (void)ws_size;
    const float* coords = (const float*)d_in[0];
    const float* sdf    = (const float*)d_in[1];
    const float* params = (const float*)d_in[2];
    const float* Wb0    = (const float*)d_in[3];
    const float* bb0    = (const float*)d_in[4];
    const float* Wb     = (const float*)d_in[5];
    const float* bb     = (const float*)d_in[6];
    const float* Wbf    = (const float*)d_in[7];
    const float* bbf    = (const float*)d_in[8];
    const float* ab     = (const float*)d_in[9];
    const float* wb     = (const float*)d_in[10];
    const float* Wt0    = (const float*)d_in[11];
    const float* bt0    = (const float*)d_in[12];
    const float* Wt     = (const float*)d_in[13];
    const float* bt     = (const float*)d_in[14];
    const float* Wtf    = (const float*)d_in[15];
    const float* btf    = (const float*)d_in[16];
    const float* at     = (const float*)d_in[17];
    const float* wt     = (const float*)d_in[18];
    float* out = (float*)d_out;
    float* ws  = (float*)d_ws;

    float* g_gates = ws;                        // 8192 floats
    float* g_wcomb = ws + 8192;                 // 10240 floats
    float* g_bcomb = ws + 8192 + 10240;         // 80 floats
    ushort_t* whi = (ushort_t*)(ws + 18512);    // 49152 bf16
    ushort_t* wlo = whi + 3 * HID * HID;        // 49152 bf16

    hipLaunchKernelGGL(prep_branch_kernel, dim3(19), dim3(256), 0, stream,
                       Wt, whi, wlo,
                       params, Wb0, bb0, Wb, bb, Wbf, bbf, ab, wb, Wtf, btf,
                       g_gates, g_wcomb, g_bcomb);

    dim3 grid((NPTS + TM - 1) / TM, BATCH);
    hipLaunchKernelGGL(trunk_kernel, grid, dim3(TPB), 0, stream,
                       coords, sdf, Wt0, bt0, bt, at, wt,
                       g_gates, g_wcomb, g_bcomb, whi, wlo, out);
}

// Round 10
// 195.639 us; speedup vs baseline: 1.1808x; 1.1808x over previous
//
#include <hip/hip_runtime.h>
#include <hip/hip_bf16.h>
#include <math.h>

#define BATCH 16
#define NPTS 10000
#define HID 128
#define NOUT 5
#define TM 64
#define TPB 256

typedef unsigned short ushort_t;
typedef __attribute__((ext_vector_type(8))) short short8;      // 8 bf16 = 4 VGPRs
typedef __attribute__((ext_vector_type(4))) float f32x4;       // MFMA C/D

__device__ __forceinline__ float fast_tanh(float x) {
    float e = __expf(2.0f * x);
    return 1.0f - 2.0f / (e + 1.0f);
}
__device__ __forceinline__ float rowdy_act(float x, float a, float w) {
    return fast_tanh(x) + a * __sinf(w * x);
}
__device__ __forceinline__ ushort_t f32_to_bf16_rn(float f) {
    unsigned u = __float_as_uint(f);
    unsigned r = (u + 0x7FFFu + ((u >> 16) & 1u)) >> 16;
    return (ushort_t)r;
}
__device__ __forceinline__ float bf16_to_f32(ushort_t u) {
    return __uint_as_float(((unsigned)u) << 16);
}

// ============ Fused prep (blocks 0-2, R6-verbatim) + branch (blocks 3-18, latency-fixed) ============
__global__ __launch_bounds__(256) void prep_branch_kernel(
    const float* __restrict__ Wt, ushort_t* __restrict__ whi, ushort_t* __restrict__ wlo,
    const float* __restrict__ params, const float* __restrict__ Wb0, const float* __restrict__ bb0,
    const float* __restrict__ Wb, const float* __restrict__ bbv,
    const float* __restrict__ Wbf, const float* __restrict__ bbf,
    const float* __restrict__ ab, const float* __restrict__ wb,
    const float* __restrict__ Wtf, const float* __restrict__ btf,
    float* __restrict__ g_gates, float* __restrict__ g_wcomb, float* __restrict__ g_bcomb)
{
    __shared__ __align__(16) float wsh[HID * HID];   // 64 KB (prep staging)
    __shared__ __align__(16) float hbuf[HID];
    __shared__ __align__(16) float pred[8 * HID];    // 8-way k-split partials
    __shared__ __align__(16) float bcbuf[NOUT * HID];
    __shared__ __align__(16) float wcred[2 * NOUT * HID];

    const int tid = threadIdx.x;

    if (blockIdx.x < 3) {
        // ---------------- prep: one block per trunk layer (R6-proven) ----------------
        const int l = blockIdx.x;
        const float4* src = (const float4*)(Wt + l * HID * HID);
        #pragma unroll
        for (int i = 0; i < 16; i++)
            ((float4*)wsh)[i * 256 + tid] = src[i * 256 + tid];
        __syncthreads();
        for (int e = tid; e < 2048; e += 256) {
            int t = e >> 8, s = (e >> 6) & 3, lam = e & 63;
            int k0 = s * 32 + (lam >> 4) * 8;
            int n = t * 16 + (lam & 15);
            short8 h8, l8;
            #pragma unroll
            for (int j = 0; j < 8; j++) {
                float v = wsh[(k0 + j) * HID + n];
                ushort_t h = f32_to_bf16_rn(v);
                float rem = v - bf16_to_f32(h);
                h8[j] = (short)h;
                l8[j] = (short)f32_to_bf16_rn(rem);
            }
            ((short8*)whi)[l * 2048 + e] = h8;
            ((short8*)wlo)[l * 2048 + e] = l8;
        }
        return;
    }

    // ---------------- branch: one block per batch ----------------
    // GEMV mapping: jg = tid&31 (4 outputs j=4*jg..), ks = tid>>5 (16 k's each)
    const int b = blockIdx.x - 3;
    const int j = tid & 127;
    const bool act = (tid < 128);
    const int jg = tid & 31;
    const int ks = tid >> 5;

    // L0 (K=6): all threads redundant on j
    {
        float z = bb0[j];
        #pragma unroll
        for (int k = 0; k < 6; k++) z += params[b * 6 + k] * Wb0[k * HID + j];
        float h = rowdy_act(z, ab[j], wb[j]);
        if (act) {
            g_gates[b * 4 * HID + j] = h;     // gate[0] = h0
            hbuf[j] = h;
        }
    }
    __syncthreads();

    float g = (act) ? g_gates[b * 4 * HID + j] : 0.f;   // re-read not needed; but keep register path:
    // (g currently = gate0 for act threads via store above; recompute locally to avoid global reread)
    // NOTE: act threads' local h was stored; rebuild g:
    if (act) g = hbuf[j];

    // 3 hidden layers: 8-way k-split, float4-j loads (16 independent loads/thread)
    for (int i = 0; i < 3; i++) {
        const float4* W4 = (const float4*)(Wb + i * HID * HID);
        float4 acc = make_float4(0.f, 0.f, 0.f, 0.f);
        #pragma unroll
        for (int kk = 0; kk < 16; kk++) {
            int k = ks * 16 + kk;
            float4 wv = W4[k * 32 + jg];
            float hv = hbuf[k];
            acc.x += hv * wv.x;
            acc.y += hv * wv.y;
            acc.z += hv * wv.z;
            acc.w += hv * wv.w;
        }
        *(float4*)&pred[ks * HID + 4 * jg] = acc;
        __syncthreads();
        float hn = 0.f;
        if (act) {
            float zz = bbv[i * HID + j];
            #pragma unroll
            for (int s = 0; s < 8; s++) zz += pred[s * HID + j];
            hn = rowdy_act(zz, ab[(i + 1) * HID + j], wb[(i + 1) * HID + j]);
            g += hn;
            g_gates[b * 4 * HID + (i + 1) * HID + j] = g;
        }
        __syncthreads();          // pred reads done before next phase overwrites
        if (act) hbuf[j] = hn;
        __syncthreads();
    }

    // branch_out: five 128-col chunks of Wbf (K=128), same mapping
    for (int o = 0; o < NOUT; o++) {
        const float4* W4 = (const float4*)Wbf;   // row stride 160 float4
        float4 acc = make_float4(0.f, 0.f, 0.f, 0.f);
        #pragma unroll
        for (int kk = 0; kk < 16; kk++) {
            int k = ks * 16 + kk;
            float4 wv = W4[k * 160 + o * 32 + jg];
            float hv = hbuf[k];
            acc.x += hv * wv.x;
            acc.y += hv * wv.y;
            acc.z += hv * wv.z;
            acc.w += hv * wv.w;
        }
        *(float4*)&pred[ks * HID + 4 * jg] = acc;
        __syncthreads();
        if (act) {
            float s = bbf[o * HID + j];
            #pragma unroll
            for (int sI = 0; sI < 8; sI++) s += pred[sI * HID + j];
            bcbuf[o * HID + j] = s;
        }
        __syncthreads();          // pred reads done before next o
    }

    // Wcomb[b][j][o] = sum_h Wtf[j][h] * bc[o][h]; (jj, h-half) mapping, float4 row reads
    {
        const int jj = tid & 127;
        const int hs = tid >> 7;             // 0/1
        const float4* Wtf4 = (const float4*)Wtf;
        float wc[NOUT] = {0.f, 0.f, 0.f, 0.f, 0.f};
        #pragma unroll
        for (int h4 = 0; h4 < 16; h4++) {
            float4 wv = Wtf4[jj * 32 + hs * 16 + h4];
            int h2 = hs * 64 + h4 * 4;
            #pragma unroll
            for (int o = 0; o < NOUT; o++) {
                float4 bv = *(const float4*)&bcbuf[o * HID + h2];
                wc[o] += wv.x * bv.x + wv.y * bv.y + wv.z * bv.z + wv.w * bv.w;
            }
        }
        #pragma unroll
        for (int o = 0; o < NOUT; o++) wcred[(hs * NOUT + o) * HID + jj] = wc[o];
        __syncthreads();
        if (act) {
            #pragma unroll
            for (int o = 0; o < NOUT; o++)
                g_wcomb[b * HID * NOUT + jj * NOUT + o] =
                    wcred[o * HID + jj] + wcred[(NOUT + o) * HID + jj];
        }
        if (tid < NOUT) {
            float acc = 0.f;
            for (int h2 = 0; h2 < HID; h2++) acc += btf[h2] * bcbuf[tid * HID + h2];
            g_bcomb[b * NOUT + tid] = acc;
        }
    }
}

// ============ Trunk kernel: round-6 version VERBATIM (known-good) ============
__global__ __launch_bounds__(TPB, 3) void trunk_kernel(
    const float* __restrict__ coords, const float* __restrict__ sdf,
    const float* __restrict__ Wt0, const float* __restrict__ bt0,
    const float* __restrict__ bt, const float* __restrict__ at, const float* __restrict__ wt,
    const float* __restrict__ g_gates, const float* __restrict__ g_wcomb,
    const float* __restrict__ g_bcomb,
    const ushort_t* __restrict__ whi, const ushort_t* __restrict__ wlo,
    float* __restrict__ out)
{
    __shared__ __align__(16) ushort_t xfh[TM * HID];            // 16 KB bf16 hi (truncated)
    __shared__ __align__(16) ushort_t xfl[TM * HID];            // 16 KB bf16 lo (truncated remainder)
    __shared__ __align__(16) float sb_bias[4][HID];
    __shared__ __align__(16) float sb_a[4][HID];
    __shared__ __align__(16) float sb_w[4][HID];
    __shared__ __align__(16) float sb_g[4][HID];
    __shared__ __align__(16) float Wt0s[4][HID];
    __shared__ __align__(16) float Wc[NOUT][HID];
    __shared__ float bcs[NOUT];
    __shared__ __align__(16) float xin[TM][4];
    __shared__ float redbuf[4][TM][NOUT];

    const int b = blockIdx.y;
    const int p0 = blockIdx.x * TM;
    const int tid = threadIdx.x;
    const int w = tid >> 6;
    const int lam = tid & 63;
    const int quad = lam >> 4, lq = lam & 15;

    for (int idx = tid; idx < 4 * HID; idx += TPB) {
        int l = idx >> 7, jj = idx & (HID - 1);
        sb_bias[l][jj] = (l == 0) ? bt0[jj] : bt[(l - 1) * HID + jj];
        sb_a[l][jj] = at[idx];
        sb_w[l][jj] = wt[idx];
        sb_g[l][jj] = g_gates[b * 4 * HID + idx];
        Wt0s[l][jj] = Wt0[idx];
    }
    for (int idx = tid; idx < HID * NOUT; idx += TPB) {
        int k = idx / NOUT, o = idx - k * NOUT;
        Wc[o][k] = g_wcomb[b * HID * NOUT + idx];
    }
    if (tid < NOUT) bcs[tid] = g_bcomb[b * NOUT + tid];

    if (tid < 192) {
        int p = tid / 3, c = tid - p * 3;
        int gp = p0 + p;
        xin[p][c] = (gp < NPTS) ? coords[(size_t)(b * NPTS + gp) * 3 + c] : 0.0f;
    } else {
        int p = tid - 192;
        int gp = p0 + p;
        xin[p][3] = (gp < NPTS) ? sdf[b * NPTS + gp] : 0.0f;
    }
    __syncthreads();

    {
        const int s = w;
        float w0c[8], w1c[8], w2c[8], w3c[8], bc8[8], ac[8], wc8[8], gc[8];
        #pragma unroll
        for (int jj = 0; jj < 8; jj++) {
            int col = s * 32 + quad * 8 + jj;
            w0c[jj] = Wt0s[0][col];
            w1c[jj] = Wt0s[1][col];
            w2c[jj] = Wt0s[2][col];
            w3c[jj] = Wt0s[3][col];
            bc8[jj] = sb_bias[0][col];
            ac[jj] = sb_a[0][col];
            wc8[jj] = sb_w[0][col];
            gc[jj] = sb_g[0][col];
        }
        #pragma unroll
        for (int mt = 0; mt < 4; mt++) {
            int row = mt * 16 + lq;
            float4 xi = *(const float4*)&xin[row][0];
            float y[8];
            #pragma unroll
            for (int jj = 0; jj < 8; jj++) {
                float zv = xi.x * w0c[jj] + xi.y * w1c[jj] + xi.z * w2c[jj] + xi.w * w3c[jj] + bc8[jj];
                y[jj] = rowdy_act(zv, ac[jj], wc8[jj]) * gc[jj];
            }
            uint4 hp, lp;
            unsigned* hpp = (unsigned*)&hp;
            unsigned* lpp = (unsigned*)&lp;
            #pragma unroll
            for (int pr = 0; pr < 4; pr++) {
                unsigned ue = __float_as_uint(y[2 * pr]);
                unsigned uo = __float_as_uint(y[2 * pr + 1]);
                hpp[pr] = (ue >> 16) | (uo & 0xFFFF0000u);
                float le = y[2 * pr] - __uint_as_float(ue & 0xFFFF0000u);
                float lo_ = y[2 * pr + 1] - __uint_as_float(uo & 0xFFFF0000u);
                lpp[pr] = (__float_as_uint(le) >> 16) | (__float_as_uint(lo_) & 0xFFFF0000u);
            }
            *(uint4*)&xfh[((mt * 4 + s) * 64 + lam) * 8] = hp;
            *(uint4*)&xfl[((mt * 4 + s) * 64 + lam) * 8] = lp;
        }
    }
    __syncthreads();

    const short8* Wh8 = (const short8*)whi;
    const short8* Wl8 = (const short8*)wlo;
    const int lq3 = lq >> 3;
    const int jlow = lq & 7;
    const int ebase0 = w * 512 + (lq3 * 16 + quad * 4) * 8 + jlow;          // nt = 2w
    const int ebase1 = w * 512 + ((2 + lq3) * 16 + quad * 4) * 8 + jlow;    // nt = 2w+1
    const int n0 = 32 * w + lq, n1 = 32 * w + 16 + lq;

    for (int l = 1; l <= 3; l++) {
        const int fb = (l - 1) * 32;
        float b0 = sb_bias[l][n0], b1 = sb_bias[l][n1];
        f32x4 acc[4][2];
        #pragma unroll
        for (int mt = 0; mt < 4; mt++) {
            acc[mt][0] = (f32x4){b0, b0, b0, b0};
            acc[mt][1] = (f32x4){b1, b1, b1, b1};
        }
        for (int s = 0; s < 4; s++) {
            short8 bh0 = Wh8[(size_t)(fb + (2 * w) * 4 + s) * 64 + lam];
            short8 bl0 = Wl8[(size_t)(fb + (2 * w) * 4 + s) * 64 + lam];
            short8 bh1 = Wh8[(size_t)(fb + (2 * w + 1) * 4 + s) * 64 + lam];
            short8 bl1 = Wl8[(size_t)(fb + (2 * w + 1) * 4 + s) * 64 + lam];
            #pragma unroll
            for (int mt = 0; mt < 4; mt++) {
                short8 ah = *(const short8*)&xfh[((mt * 4 + s) * 64 + lam) * 8];
                short8 al = *(const short8*)&xfl[((mt * 4 + s) * 64 + lam) * 8];
                acc[mt][0] = __builtin_amdgcn_mfma_f32_16x16x32_bf16(ah, bh0, acc[mt][0], 0, 0, 0);
                acc[mt][0] = __builtin_amdgcn_mfma_f32_16x16x32_bf16(al, bh0, acc[mt][0], 0, 0, 0);
                acc[mt][0] = __builtin_amdgcn_mfma_f32_16x16x32_bf16(ah, bl0, acc[mt][0], 0, 0, 0);
                acc[mt][1] = __builtin_amdgcn_mfma_f32_16x16x32_bf16(ah, bh1, acc[mt][1], 0, 0, 0);
                acc[mt][1] = __builtin_amdgcn_mfma_f32_16x16x32_bf16(al, bh1, acc[mt][1], 0, 0, 0);
                acc[mt][1] = __builtin_amdgcn_mfma_f32_16x16x32_bf16(ah, bl1, acc[mt][1], 0, 0, 0);
            }
        }
        __syncthreads();
        float a0 = sb_a[l][n0], ww0 = sb_w[l][n0], gg0 = sb_g[l][n0];
        float a1 = sb_a[l][n1], ww1 = sb_w[l][n1], gg1 = sb_g[l][n1];
        #pragma unroll
        for (int mt = 0; mt < 4; mt++) {
            #pragma unroll
            for (int r = 0; r < 4; r++) {
                float y0 = rowdy_act(acc[mt][0][r], a0, ww0) * gg0;
                float y1 = rowdy_act(acc[mt][1][r], a1, ww1) * gg1;
                unsigned u0 = __float_as_uint(y0);
                unsigned u1 = __float_as_uint(y1);
                float l0f = y0 - __uint_as_float(u0 & 0xFFFF0000u);
                float l1f = y1 - __uint_as_float(u1 & 0xFFFF0000u);
                xfh[mt * 2048 + ebase0 + r * 8] = (ushort_t)(u0 >> 16);
                xfl[mt * 2048 + ebase0 + r * 8] = (ushort_t)(__float_as_uint(l0f) >> 16);
                xfh[mt * 2048 + ebase1 + r * 8] = (ushort_t)(u1 >> 16);
                xfl[mt * 2048 + ebase1 + r * 8] = (ushort_t)(__float_as_uint(l1f) >> 16);
            }
        }
        __syncthreads();
    }

    {
        int q = tid & 3, p = tid >> 2;
        int mt = p >> 4, prow = p & 15;
        float part[NOUT] = {0.f, 0.f, 0.f, 0.f, 0.f};
        #pragma unroll
        for (int g8 = 0; g8 < 4; g8++) {
            int base = ((mt * 4 + q) * 64 + g8 * 16 + prow) * 8;
            uint4 h4 = *(const uint4*)&xfh[base];
            uint4 l4 = *(const uint4*)&xfl[base];
            const unsigned* hu = (const unsigned*)&h4;
            const unsigned* lu = (const unsigned*)&l4;
            int c0 = q * 32 + g8 * 8;
            float xv[8];
            #pragma unroll
            for (int pr = 0; pr < 4; pr++) {
                xv[2 * pr]     = __uint_as_float(hu[pr] << 16) + __uint_as_float(lu[pr] << 16);
                xv[2 * pr + 1] = __uint_as_float(hu[pr] & 0xFFFF0000u) + __uint_as_float(lu[pr] & 0xFFFF0000u);
            }
            #pragma unroll
            for (int o = 0; o < NOUT; o++) {
                float4 wa = *(const float4*)&Wc[o][c0];
                float4 wb4 = *(const float4*)&Wc[o][c0 + 4];
                part[o] += xv[0] * wa.x + xv[1] * wa.y + xv[2] * wa.z + xv[3] * wa.w
                         + xv[4] * wb4.x + xv[5] * wb4.y + xv[6] * wb4.z + xv[7] * wb4.w;
            }
        }
        #pragma unroll
        for (int o = 0; o < NOUT; o++) redbuf[q][p][o] = part[o];
    }
    __syncthreads();
    if (tid < TM) {
        int gp = p0 + tid;
        if (gp < NPTS) {
            #pragma unroll
            for (int o = 0; o < NOUT; o++) {
                float s = bcs[o] + redbuf[0][tid][o] + redbuf[1][tid][o]
                                 + redbuf[2][tid][o] + redbuf[3][tid][o];
                out[(size_t)(b * NPTS + gp) * NOUT + o] = s;
            }
        }
    }
}

extern "C" void kernel_launch(void* const* d_in, const int* in_sizes, int n_in,
                              void* d_out, int out_size, void* d_ws, size_t ws_size,
                              hipStream_t stream) {
    (void)in_sizes; (void)n_in; (void)out_size; (void)ws_size;
    const float* coords = (const float*)d_in[0];
    const float* sdf    = (const float*)d_in[1];
    const float* params = (const float*)d_in[2];
    const float* Wb0    = (const float*)d_in[3];
    const float* bb0    = (const float*)d_in[4];
    const float* Wb     = (const float*)d_in[5];
    const float* bbv    = (const float*)d_in[6];
    const float* Wbf    = (const float*)d_in[7];
    const float* bbf    = (const float*)d_in[8];
    const float* ab     = (const float*)d_in[9];
    const float* wb     = (const float*)d_in[10];
    const float* Wt0    = (const float*)d_in[11];
    const float* bt0    = (const float*)d_in[12];
    const float* Wt     = (const float*)d_in[13];
    const float* bt     = (const float*)d_in[14];
    const float* Wtf    = (const float*)d_in[15];
    const float* btf    = (const float*)d_in[16];
    const float* at     = (const float*)d_in[17];
    const float* wt     = (const float*)d_in[18];
    float* out = (float*)d_out;
    float* ws  = (float*)d_ws;

    float* g_gates = ws;                        // 8192 floats
    float* g_wcomb = ws + 8192;                 // 10240 floats
    float* g_bcomb = ws + 8192 + 10240;         // 80 floats
    ushort_t* whi = (ushort_t*)(ws + 18512);    // 49152 bf16
    ushort_t* wlo = whi + 3 * HID * HID;        // 49152 bf16

    hipLaunchKernelGGL(prep_branch_kernel, dim3(19), dim3(256), 0, stream,
                       Wt, whi, wlo,
                       params, Wb0, bb0, Wb, bbv, Wbf, bbf, ab, wb, Wtf, btf,
                       g_gates, g_wcomb, g_bcomb);

    dim3 grid((NPTS + TM - 1) / TM, BATCH);
    hipLaunchKernelGGL(trunk_kernel, grid, dim3(TPB), 0, stream,
                       coords, sdf, Wt0, bt0, bt, at, wt,
                       g_gates, g_wcomb, g_bcomb, whi, wlo, out);
}

// Round 11
// 184.962 us; speedup vs baseline: 1.2490x; 1.0577x over previous
//
#include <hip/hip_runtime.h>
#include <hip/hip_bf16.h>
#include <math.h>

#define BATCH 16
#define NPTS 10000
#define HID 128
#define NOUT 5
#define TM 64
#define TPB 256

typedef unsigned short ushort_t;
typedef __attribute__((ext_vector_type(8))) short short8;      // 8 bf16 = 4 VGPRs
typedef __attribute__((ext_vector_type(4))) float f32x4;       // MFMA C/D

__device__ __forceinline__ float fast_tanh(float x) {
    // tanh(x) = 1 - 2/(e^{2x}+1); v_rcp_f32 (1 ulp) instead of precise div
    // (saves the ~10-inst v_div_scale/fmas/fixup sequence per value).
    // x -> +inf: e=inf, rcp=0, tanh=1; x -> -inf: e=0, rcp(1)=1, tanh=-1. Correct limits.
    float e = __expf(2.0f * x);
    return 1.0f - 2.0f * __builtin_amdgcn_rcpf(e + 1.0f);
}
__device__ __forceinline__ float rowdy_act(float x, float a, float w) {
    return fast_tanh(x) + a * __sinf(w * x);
}
__device__ __forceinline__ ushort_t f32_to_bf16_rn(float f) {
    unsigned u = __float_as_uint(f);
    unsigned r = (u + 0x7FFFu + ((u >> 16) & 1u)) >> 16;
    return (ushort_t)r;
}
__device__ __forceinline__ float bf16_to_f32(ushort_t u) {
    return __uint_as_float(((unsigned)u) << 16);
}

// ============ Fused prep (blocks 0-2) + branch (blocks 3-18, latency-fixed) ============
__global__ __launch_bounds__(256) void prep_branch_kernel(
    const float* __restrict__ Wt, ushort_t* __restrict__ whi, ushort_t* __restrict__ wlo,
    const float* __restrict__ params, const float* __restrict__ Wb0, const float* __restrict__ bb0,
    const float* __restrict__ Wb, const float* __restrict__ bbv,
    const float* __restrict__ Wbf, const float* __restrict__ bbf,
    const float* __restrict__ ab, const float* __restrict__ wb,
    const float* __restrict__ Wtf, const float* __restrict__ btf,
    float* __restrict__ g_gates, float* __restrict__ g_wcomb, float* __restrict__ g_bcomb)
{
    __shared__ __align__(16) float wsh[HID * HID];   // 64 KB (prep staging)
    __shared__ __align__(16) float hbuf[HID];
    __shared__ __align__(16) float pred[8 * HID];    // 8-way k-split partials
    __shared__ __align__(16) float bcbuf[NOUT * HID];
    __shared__ __align__(16) float wcred[2 * NOUT * HID];

    const int tid = threadIdx.x;

    if (blockIdx.x < 3) {
        // ---------------- prep: one block per trunk layer ----------------
        const int l = blockIdx.x;
        const float4* src = (const float4*)(Wt + l * HID * HID);
        #pragma unroll
        for (int i = 0; i < 16; i++)
            ((float4*)wsh)[i * 256 + tid] = src[i * 256 + tid];
        __syncthreads();
        for (int e = tid; e < 2048; e += 256) {
            int t = e >> 8, s = (e >> 6) & 3, lam = e & 63;
            int k0 = s * 32 + (lam >> 4) * 8;
            int n = t * 16 + (lam & 15);
            short8 h8, l8;
            #pragma unroll
            for (int j = 0; j < 8; j++) {
                float v = wsh[(k0 + j) * HID + n];
                ushort_t h = f32_to_bf16_rn(v);
                float rem = v - bf16_to_f32(h);
                h8[j] = (short)h;
                l8[j] = (short)f32_to_bf16_rn(rem);
            }
            ((short8*)whi)[l * 2048 + e] = h8;
            ((short8*)wlo)[l * 2048 + e] = l8;
        }
        return;
    }

    // ---------------- branch: one block per batch ----------------
    const int b = blockIdx.x - 3;
    const int j = tid & 127;
    const bool act = (tid < 128);
    const int jg = tid & 31;
    const int ks = tid >> 5;

    // L0 (K=6): all threads redundant on j
    {
        float z = bb0[j];
        #pragma unroll
        for (int k = 0; k < 6; k++) z += params[b * 6 + k] * Wb0[k * HID + j];
        float h = rowdy_act(z, ab[j], wb[j]);
        if (act) {
            g_gates[b * 4 * HID + j] = h;     // gate[0] = h0
            hbuf[j] = h;
        }
    }
    __syncthreads();

    float g = 0.f;
    if (act) g = hbuf[j];

    // 3 hidden layers: 8-way k-split, float4-j loads (16 independent loads/thread)
    for (int i = 0; i < 3; i++) {
        const float4* W4 = (const float4*)(Wb + i * HID * HID);
        float4 acc = make_float4(0.f, 0.f, 0.f, 0.f);
        #pragma unroll
        for (int kk = 0; kk < 16; kk++) {
            int k = ks * 16 + kk;
            float4 wv = W4[k * 32 + jg];
            float hv = hbuf[k];
            acc.x += hv * wv.x;
            acc.y += hv * wv.y;
            acc.z += hv * wv.z;
            acc.w += hv * wv.w;
        }
        *(float4*)&pred[ks * HID + 4 * jg] = acc;
        __syncthreads();
        float hn = 0.f;
        if (act) {
            float zz = bbv[i * HID + j];
            #pragma unroll
            for (int s = 0; s < 8; s++) zz += pred[s * HID + j];
            hn = rowdy_act(zz, ab[(i + 1) * HID + j], wb[(i + 1) * HID + j]);
            g += hn;
            g_gates[b * 4 * HID + (i + 1) * HID + j] = g;
        }
        __syncthreads();          // pred reads done before next phase overwrites
        if (act) hbuf[j] = hn;
        __syncthreads();
    }

    // branch_out: five 128-col chunks of Wbf (K=128), same mapping
    for (int o = 0; o < NOUT; o++) {
        const float4* W4 = (const float4*)Wbf;   // row stride 160 float4
        float4 acc = make_float4(0.f, 0.f, 0.f, 0.f);
        #pragma unroll
        for (int kk = 0; kk < 16; kk++) {
            int k = ks * 16 + kk;
            float4 wv = W4[k * 160 + o * 32 + jg];
            float hv = hbuf[k];
            acc.x += hv * wv.x;
            acc.y += hv * wv.y;
            acc.z += hv * wv.z;
            acc.w += hv * wv.w;
        }
        *(float4*)&pred[ks * HID + 4 * jg] = acc;
        __syncthreads();
        if (act) {
            float s = bbf[o * HID + j];
            #pragma unroll
            for (int sI = 0; sI < 8; sI++) s += pred[sI * HID + j];
            bcbuf[o * HID + j] = s;
        }
        __syncthreads();          // pred reads done before next o
    }

    // Wcomb[b][j][o] = sum_h Wtf[j][h] * bc[o][h]; (jj, h-half) mapping, float4 row reads
    {
        const int jj = tid & 127;
        const int hs = tid >> 7;             // 0/1
        const float4* Wtf4 = (const float4*)Wtf;
        float wc[NOUT] = {0.f, 0.f, 0.f, 0.f, 0.f};
        #pragma unroll
        for (int h4 = 0; h4 < 16; h4++) {
            float4 wv = Wtf4[jj * 32 + hs * 16 + h4];
            int h2 = hs * 64 + h4 * 4;
            #pragma unroll
            for (int o = 0; o < NOUT; o++) {
                float4 bv = *(const float4*)&bcbuf[o * HID + h2];
                wc[o] += wv.x * bv.x + wv.y * bv.y + wv.z * bv.z + wv.w * bv.w;
            }
        }
        #pragma unroll
        for (int o = 0; o < NOUT; o++) wcred[(hs * NOUT + o) * HID + jj] = wc[o];
        __syncthreads();
        if (act) {
            #pragma unroll
            for (int o = 0; o < NOUT; o++)
                g_wcomb[b * HID * NOUT + jj * NOUT + o] =
                    wcred[o * HID + jj] + wcred[(NOUT + o) * HID + jj];
        }
        if (tid < NOUT) {
            float acc = 0.f;
            for (int h2 = 0; h2 < HID; h2++) acc += btf[h2] * bcbuf[tid * HID + h2];
            g_bcomb[b * NOUT + tid] = acc;
        }
    }
}

// ============ Trunk kernel: round-6 structure (known-good), rcp-tanh ============
__global__ __launch_bounds__(TPB, 3) void trunk_kernel(
    const float* __restrict__ coords, const float* __restrict__ sdf,
    const float* __restrict__ Wt0, const float* __restrict__ bt0,
    const float* __restrict__ bt, const float* __restrict__ at, const float* __restrict__ wt,
    const float* __restrict__ g_gates, const float* __restrict__ g_wcomb,
    const float* __restrict__ g_bcomb,
    const ushort_t* __restrict__ whi, const ushort_t* __restrict__ wlo,
    float* __restrict__ out)
{
    __shared__ __align__(16) ushort_t xfh[TM * HID];            // 16 KB bf16 hi (truncated)
    __shared__ __align__(16) ushort_t xfl[TM * HID];            // 16 KB bf16 lo (truncated remainder)
    __shared__ __align__(16) float sb_bias[4][HID];
    __shared__ __align__(16) float sb_a[4][HID];
    __shared__ __align__(16) float sb_w[4][HID];
    __shared__ __align__(16) float sb_g[4][HID];
    __shared__ __align__(16) float Wt0s[4][HID];
    __shared__ __align__(16) float Wc[NOUT][HID];
    __shared__ float bcs[NOUT];
    __shared__ __align__(16) float xin[TM][4];
    __shared__ float redbuf[4][TM][NOUT];

    const int b = blockIdx.y;
    const int p0 = blockIdx.x * TM;
    const int tid = threadIdx.x;
    const int w = tid >> 6;
    const int lam = tid & 63;
    const int quad = lam >> 4, lq = lam & 15;

    for (int idx = tid; idx < 4 * HID; idx += TPB) {
        int l = idx >> 7, jj = idx & (HID - 1);
        sb_bias[l][jj] = (l == 0) ? bt0[jj] : bt[(l - 1) * HID + jj];
        sb_a[l][jj] = at[idx];
        sb_w[l][jj] = wt[idx];
        sb_g[l][jj] = g_gates[b * 4 * HID + idx];
        Wt0s[l][jj] = Wt0[idx];
    }
    for (int idx = tid; idx < HID * NOUT; idx += TPB) {
        int k = idx / NOUT, o = idx - k * NOUT;
        Wc[o][k] = g_wcomb[b * HID * NOUT + idx];
    }
    if (tid < NOUT) bcs[tid] = g_bcomb[b * NOUT + tid];

    if (tid < 192) {
        int p = tid / 3, c = tid - p * 3;
        int gp = p0 + p;
        xin[p][c] = (gp < NPTS) ? coords[(size_t)(b * NPTS + gp) * 3 + c] : 0.0f;
    } else {
        int p = tid - 192;
        int gp = p0 + p;
        xin[p][3] = (gp < NPTS) ? sdf[b * NPTS + gp] : 0.0f;
    }
    __syncthreads();

    {
        const int s = w;
        float w0c[8], w1c[8], w2c[8], w3c[8], bc8[8], ac[8], wc8[8], gc[8];
        #pragma unroll
        for (int jj = 0; jj < 8; jj++) {
            int col = s * 32 + quad * 8 + jj;
            w0c[jj] = Wt0s[0][col];
            w1c[jj] = Wt0s[1][col];
            w2c[jj] = Wt0s[2][col];
            w3c[jj] = Wt0s[3][col];
            bc8[jj] = sb_bias[0][col];
            ac[jj] = sb_a[0][col];
            wc8[jj] = sb_w[0][col];
            gc[jj] = sb_g[0][col];
        }
        #pragma unroll
        for (int mt = 0; mt < 4; mt++) {
            int row = mt * 16 + lq;
            float4 xi = *(const float4*)&xin[row][0];
            float y[8];
            #pragma unroll
            for (int jj = 0; jj < 8; jj++) {
                float zv = xi.x * w0c[jj] + xi.y * w1c[jj] + xi.z * w2c[jj] + xi.w * w3c[jj] + bc8[jj];
                y[jj] = rowdy_act(zv, ac[jj], wc8[jj]) * gc[jj];
            }
            uint4 hp, lp;
            unsigned* hpp = (unsigned*)&hp;
            unsigned* lpp = (unsigned*)&lp;
            #pragma unroll
            for (int pr = 0; pr < 4; pr++) {
                unsigned ue = __float_as_uint(y[2 * pr]);
                unsigned uo = __float_as_uint(y[2 * pr + 1]);
                hpp[pr] = (ue >> 16) | (uo & 0xFFFF0000u);
                float le = y[2 * pr] - __uint_as_float(ue & 0xFFFF0000u);
                float lo_ = y[2 * pr + 1] - __uint_as_float(uo & 0xFFFF0000u);
                lpp[pr] = (__float_as_uint(le) >> 16) | (__float_as_uint(lo_) & 0xFFFF0000u);
            }
            *(uint4*)&xfh[((mt * 4 + s) * 64 + lam) * 8] = hp;
            *(uint4*)&xfl[((mt * 4 + s) * 64 + lam) * 8] = lp;
        }
    }
    __syncthreads();

    const short8* Wh8 = (const short8*)whi;
    const short8* Wl8 = (const short8*)wlo;
    const int lq3 = lq >> 3;
    const int jlow = lq & 7;
    const int ebase0 = w * 512 + (lq3 * 16 + quad * 4) * 8 + jlow;          // nt = 2w
    const int ebase1 = w * 512 + ((2 + lq3) * 16 + quad * 4) * 8 + jlow;    // nt = 2w+1
    const int n0 = 32 * w + lq, n1 = 32 * w + 16 + lq;

    for (int l = 1; l <= 3; l++) {
        const int fb = (l - 1) * 32;
        float b0 = sb_bias[l][n0], b1 = sb_bias[l][n1];
        f32x4 acc[4][2];
        #pragma unroll
        for (int mt = 0; mt < 4; mt++) {
            acc[mt][0] = (f32x4){b0, b0, b0, b0};
            acc[mt][1] = (f32x4){b1, b1, b1, b1};
        }
        for (int s = 0; s < 4; s++) {
            short8 bh0 = Wh8[(size_t)(fb + (2 * w) * 4 + s) * 64 + lam];
            short8 bl0 = Wl8[(size_t)(fb + (2 * w) * 4 + s) * 64 + lam];
            short8 bh1 = Wh8[(size_t)(fb + (2 * w + 1) * 4 + s) * 64 + lam];
            short8 bl1 = Wl8[(size_t)(fb + (2 * w + 1) * 4 + s) * 64 + lam];
            #pragma unroll
            for (int mt = 0; mt < 4; mt++) {
                short8 ah = *(const short8*)&xfh[((mt * 4 + s) * 64 + lam) * 8];
                short8 al = *(const short8*)&xfl[((mt * 4 + s) * 64 + lam) * 8];
                acc[mt][0] = __builtin_amdgcn_mfma_f32_16x16x32_bf16(ah, bh0, acc[mt][0], 0, 0, 0);
                acc[mt][0] = __builtin_amdgcn_mfma_f32_16x16x32_bf16(al, bh0, acc[mt][0], 0, 0, 0);
                acc[mt][0] = __builtin_amdgcn_mfma_f32_16x16x32_bf16(ah, bl0, acc[mt][0], 0, 0, 0);
                acc[mt][1] = __builtin_amdgcn_mfma_f32_16x16x32_bf16(ah, bh1, acc[mt][1], 0, 0, 0);
                acc[mt][1] = __builtin_amdgcn_mfma_f32_16x16x32_bf16(al, bh1, acc[mt][1], 0, 0, 0);
                acc[mt][1] = __builtin_amdgcn_mfma_f32_16x16x32_bf16(ah, bl1, acc[mt][1], 0, 0, 0);
            }
        }
        __syncthreads();
        float a0 = sb_a[l][n0], ww0 = sb_w[l][n0], gg0 = sb_g[l][n0];
        float a1 = sb_a[l][n1], ww1 = sb_w[l][n1], gg1 = sb_g[l][n1];
        #pragma unroll
        for (int mt = 0; mt < 4; mt++) {
            #pragma unroll
            for (int r = 0; r < 4; r++) {
                float y0 = rowdy_act(acc[mt][0][r], a0, ww0) * gg0;
                float y1 = rowdy_act(acc[mt][1][r], a1, ww1) * gg1;
                unsigned u0 = __float_as_uint(y0);
                unsigned u1 = __float_as_uint(y1);
                float l0f = y0 - __uint_as_float(u0 & 0xFFFF0000u);
                float l1f = y1 - __uint_as_float(u1 & 0xFFFF0000u);
                xfh[mt * 2048 + ebase0 + r * 8] = (ushort_t)(u0 >> 16);
                xfl[mt * 2048 + ebase0 + r * 8] = (ushort_t)(__float_as_uint(l0f) >> 16);
                xfh[mt * 2048 + ebase1 + r * 8] = (ushort_t)(u1 >> 16);
                xfl[mt * 2048 + ebase1 + r * 8] = (ushort_t)(__float_as_uint(l1f) >> 16);
            }
        }
        __syncthreads();
    }

    {
        int q = tid & 3, p = tid >> 2;
        int mt = p >> 4, prow = p & 15;
        float part[NOUT] = {0.f, 0.f, 0.f, 0.f, 0.f};
        #pragma unroll
        for (int g8 = 0; g8 < 4; g8++) {
            int base = ((mt * 4 + q) * 64 + g8 * 16 + prow) * 8;
            uint4 h4 = *(const uint4*)&xfh[base];
            uint4 l4 = *(const uint4*)&xfl[base];
            const unsigned* hu = (const unsigned*)&h4;
            const unsigned* lu = (const unsigned*)&l4;
            int c0 = q * 32 + g8 * 8;
            float xv[8];
            #pragma unroll
            for (int pr = 0; pr < 4; pr++) {
                xv[2 * pr]     = __uint_as_float(hu[pr] << 16) + __uint_as_float(lu[pr] << 16);
                xv[2 * pr + 1] = __uint_as_float(hu[pr] & 0xFFFF0000u) + __uint_as_float(lu[pr] & 0xFFFF0000u);
            }
            #pragma unroll
            for (int o = 0; o < NOUT; o++) {
                float4 wa = *(const float4*)&Wc[o][c0];
                float4 wb4 = *(const float4*)&Wc[o][c0 + 4];
                part[o] += xv[0] * wa.x + xv[1] * wa.y + xv[2] * wa.z + xv[3] * wa.w
                         + xv[4] * wb4.x + xv[5] * wb4.y + xv[6] * wb4.z + xv[7] * wb4.w;
            }
        }
        #pragma unroll
        for (int o = 0; o < NOUT; o++) redbuf[q][p][o] = part[o];
    }
    __syncthreads();
    if (tid < TM) {
        int gp = p0 + tid;
        if (gp < NPTS) {
            #pragma unroll
            for (int o = 0; o < NOUT; o++) {
                float s = bcs[o] + redbuf[0][tid][o] + redbuf[1][tid][o]
                                 + redbuf[2][tid][o] + redbuf[3][tid][o];
                out[(size_t)(b * NPTS + gp) * NOUT + o] = s;
            }
        }
    }
}

extern "C" void kernel_launch(void* const* d_in, const int* in_sizes, int n_in,
                              void* d_out, int out_size, void* d_ws, size_t ws_size,
                              hipStream_t stream) {
    (void)in_sizes; (void)n_in; (void)out_size; (void)ws_size;
    const float* coords = (const float*)d_in[0];
    const float* sdf    = (const float*)d_in[1];
    const float* params = (const float*)d_in[2];
    const float* Wb0    = (const float*)d_in[3];
    const float* bb0    = (const float*)d_in[4];
    const float* Wb     = (const float*)d_in[5];
    const float* bbv    = (const float*)d_in[6];
    const float* Wbf    = (const float*)d_in[7];
    const float* bbf    = (const float*)d_in[8];
    const float* ab     = (const float*)d_in[9];
    const float* wb     = (const float*)d_in[10];
    const float* Wt0    = (const float*)d_in[11];
    const float* bt0    = (const float*)d_in[12];
    const float* Wt     = (const float*)d_in[13];
    const float* bt     = (const float*)d_in[14];
    const float* Wtf    = (const float*)d_in[15];
    const float* btf    = (const float*)d_in[16];
    const float* at     = (const float*)d_in[17];
    const float* wt     = (const float*)d_in[18];
    float* out = (float*)d_out;
    float* ws  = (float*)d_ws;

    float* g_gates = ws;                        // 8192 floats
    float* g_wcomb = ws + 8192;                 // 10240 floats
    float* g_bcomb = ws + 8192 + 10240;         // 80 floats
    ushort_t* whi = (ushort_t*)(ws + 18512);    // 49152 bf16
    ushort_t* wlo = whi + 3 * HID * HID;        // 49152 bf16

    hipLaunchKernelGGL(prep_branch_kernel, dim3(19), dim3(256), 0, stream,
                       Wt, whi, wlo,
                       params, Wb0, bb0, Wb, bbv, Wbf, bbf, ab, wb, Wtf, btf,
                       g_gates, g_wcomb, g_bcomb);

    dim3 grid((NPTS + TM - 1) / TM, BATCH);
    hipLaunchKernelGGL(trunk_kernel, grid, dim3(TPB), 0, stream,
                       coords, sdf, Wt0, bt0, bt, at, wt,
                       g_gates, g_wcomb, g_bcomb, whi, wlo, out);
}